// Round 6
// baseline (166.038 us; speedup 1.0000x reference)
//
#include <hip/hip_runtime.h>

// x shape (B, T, A, D) = (256, 2048, 22, 2) fp32
#define BB 256
#define TT 2048
#define AD 44                        // floats per (b,t) row
#define AD4 11                       // float4 chunks per row
#define F4_PER_B (TT * AD4)          // 22528 float4 per batch
#define F4_TOTAL (BB * F4_PER_B)     // 5,767,168 float4 total
#define NFIX BB                      // 256 fixer blocks (dispatched first)
#define NCOPY_BLK 2048               // persistent copy blocks (8/CU)
#define COPY_THREADS (NCOPY_BLK * 256)  // 524,288
#define ELEMS 11                     // F4_TOTAL / COPY_THREADS exactly
#define NBLK (NFIX + NCOPY_BLK)

typedef float v4 __attribute__((ext_vector_type(4)));

// Block-wide min/max reduce of (tmin, tmax). Result uniform in all threads.
__device__ __forceinline__ void block_minmax(const int tid, int& tmin, int& tmax,
                                             int* smin, int* smax) {
#pragma unroll
  for (int d = 32; d > 0; d >>= 1) {
    tmin = min(tmin, __shfl_xor(tmin, d));
    tmax = max(tmax, __shfl_xor(tmax, d));
  }
  const int wid = tid >> 6;
  if ((tid & 63) == 0) { smin[wid] = tmin; smax[wid] = tmax; }
  __syncthreads();
  if (tid == 0) {
    int a = smin[0], z = smax[0];
#pragma unroll
    for (int i = 1; i < 4; ++i) { a = min(a, smin[i]); z = max(z, smax[i]); }
    smin[0] = a; smax[0] = z;
  }
  __syncthreads();
  tmin = smin[0];
  tmax = smax[0];
  __syncthreads();
}

// Single dispatch, two roles, zero cross-block sync, disjoint writes.
// Copy role: PERSISTENT grid-stride blocks (2048 = 8/CU resident for the
// whole kernel -> no block churn) with 11 independent float4 loads forced
// to stay in flight via a compiler scheduling barrier. Round-5 post-mortem:
// VGPR_Count=20 proved the compiler had serialized my "8 loads in flight"
// into load/store pairs (~2 deep) -> 2.5 TB/s. The barrier forces all 11
// loads to issue before the first store; VGPR must rise to ~50-64.
// Fixer role (blockIdx < 256, dispatched first so it gets a CU slot before
// the persistent copy blocks fill the machine): per-batch NaN-range scan
// (coarse every-8th-row probe + fine edge probe, proven in round 5:
// FETCH 77.5 -> 49.5 MB) + gap interpolation. Gap-interior rows are all-NaN;
// copy skips NaN chunks, fixer writes exactly those rows -> disjoint.
__global__ __launch_bounds__(256) void interp_v6(const v4* __restrict__ x4,
                                                 v4* __restrict__ out4) {
  const int tid = threadIdx.x;

  if (blockIdx.x >= NFIX) {
    // ---------------- copy role ----------------
    const int ct = (blockIdx.x - NFIX) * 256 + tid;   // 0 .. 524287

    v4 v[ELEMS];
#pragma unroll
    for (int k = 0; k < ELEMS; ++k) {
      v[k] = x4[(size_t)ct + (size_t)k * COPY_THREADS];
    }
    // Keep all 11 loads outstanding: forbid the scheduler from sinking
    // loads below stores (which collapsed MLP to ~2 in prior rounds).
    asm volatile("" ::: "memory");
#pragma unroll
    for (int k = 0; k < ELEMS; ++k) {
      const v4 w = v[k];
      const bool n = (w.x != w.x) || (w.y != w.y) || (w.z != w.z) || (w.w != w.w);
      if (!n) out4[(size_t)ct + (size_t)k * COPY_THREADS] = w;
    }
    return;
  }

  // ---------------- fixer role ----------------
  const int b = blockIdx.x;
  const float* xf = (const float*)x4;
  const size_t fbase = (size_t)b * (TT * AD);
  __shared__ int smin[4], smax[4];

  // Coarse scan: probe column (t,0,0) every 8th row (~16KB of lines/batch).
  int tmin = TT, tmax = -1;
  {
    const int r = tid * 8;
    const float c = xf[fbase + (size_t)r * AD];
    if (c != c) { tmin = r; tmax = r; }
  }
  block_minmax(tid, tmin, tmax, smin, smax);

  if (tmax < 0) {
    // Gap (1..7 rows) fell between samples: full column scan.
    tmin = TT; tmax = -1;
#pragma unroll
    for (int k = 0; k < 8; ++k) {
      const int r = k * 256 + tid;
      const float c = xf[fbase + (size_t)r * AD];
      if (c != c) { tmin = min(tmin, r); tmax = max(tmax, r); }
    }
    block_minmax(tid, tmin, tmax, smin, smax);
  } else {
    // NaN run is contiguous: true edges within 7 rows of coarse edges.
    const int cmin = tmin, cmax = tmax;
    tmin = cmin; tmax = cmax;
    if (tid < 7) {
      const int r = cmin - 1 - tid;
      if (r >= 0) { const float c = xf[fbase + (size_t)r * AD]; if (c != c) tmin = r; }
    } else if (tid >= 64 && tid < 71) {
      const int r = cmax + 1 + (tid - 64);
      if (r < TT) { const float c = xf[fbase + (size_t)r * AD]; if (c != c) tmax = r; }
    }
    block_minmax(tid, tmin, tmax, smin, smax);
  }

  int s, e;
  if (tmax < 0) {                // defensive: no NaN -> no-op, in-bounds reads
    s = 0; e = 1;
  } else {
    s = tmin - 1;                // row before first NaN
    e = min(tmax + 1, TT - 1);   // row after last NaN (clamped for safety)
  }

  // Boundary rows (NaN-free by construction) -> LDS.
  __shared__ v4 sxs[AD4], sxe[AD4];
  const size_t base = (size_t)b * F4_PER_B;
  if (tid < AD4) sxs[tid] = x4[base + (size_t)s * AD4 + tid];
  if (tid >= 64 && tid < 64 + AD4) sxe[tid - 64] = x4[base + (size_t)e * AD4 + (tid - 64)];
  __syncthreads();

  // Interpolate gap interior rows s+1 .. e-1 (sole writer of this region).
  const float inv = 1.0f / (float)(e - s);
  const int total = (e - s - 1) * AD4;
  for (int i = tid; i < total; i += 256) {
    const int dt = i / AD4;
    const int cch = i - dt * AD4;
    const int t = s + 1 + dt;
    const float w = (float)(dt + 1) * inv;   // (t - s)/(e - s)
    const float om = 1.0f - w;
    const v4 a = sxs[cch];
    const v4 z = sxe[cch];
    v4 r;
    r.x = a.x * om + z.x * w;
    r.y = a.y * om + z.y * w;
    r.z = a.z * om + z.z * w;
    r.w = a.w * om + z.w * w;
    out4[base + (size_t)t * AD4 + cch] = r;
  }
}

extern "C" void kernel_launch(void* const* d_in, const int* in_sizes, int n_in,
                              void* d_out, int out_size, void* d_ws, size_t ws_size,
                              hipStream_t stream) {
  const v4* x4 = (const v4*)d_in[0];
  v4* out4 = (v4*)d_out;
  interp_v6<<<NBLK, 256, 0, stream>>>(x4, out4);
}

// Round 7
// 163.768 us; speedup vs baseline: 1.0139x; 1.0139x over previous
//
#include <hip/hip_runtime.h>

// x shape (B, T, A, D) = (256, 2048, 22, 2) fp32
#define BB 256
#define TT 2048
#define AD 44                    // floats per (b,t) row
#define AD4 11                   // float4 chunks per row
#define F4_PER_B (TT * AD4)      // 22528 float4 per batch
#define ELEMS 8                  // float4 per thread
#define BLK_F4 (256 * ELEMS)     // 2048 float4 per block
#define BLOCKS_PER_B 11
#define NBLK (BB * BLOCKS_PER_B) // 2816 blocks, b block-uniform

typedef float v4 __attribute__((ext_vector_type(4)));

// Block-wide min/max reduce of (tmin, tmax). Result uniform in all threads.
__device__ __forceinline__ void block_minmax(const int tid, int& tmin, int& tmax,
                                             int* smin, int* smax) {
#pragma unroll
  for (int d = 32; d > 0; d >>= 1) {
    tmin = min(tmin, __shfl_xor(tmin, d));
    tmax = max(tmax, __shfl_xor(tmax, d));
  }
  const int wid = tid >> 6;
  if ((tid & 63) == 0) { smin[wid] = tmin; smax[wid] = tmax; }
  __syncthreads();
  if (tid == 0) {
    int a = smin[0], z = smax[0];
#pragma unroll
    for (int i = 1; i < 4; ++i) { a = min(a, smin[i]); z = max(z, smax[i]); }
    smin[0] = a; smax[0] = z;
  }
  __syncthreads();
  tmin = smin[0];
  tmax = smax[0];
  __syncthreads();
}

// v7: uniform blocks, no roles, no value-dependent stores.
// Round-6 post-mortem: every variant where the loaded value gated the store
// (NaN check -> conditional store) was compiled to shallow load/check/store
// pairs (VGPR=20-24, ~4 loads in flight, 2.4-2.7 TB/s). Here the 8 main
// loads are issued via inline-asm global_load_dwordx4 (untracked, 8 outputs
// concurrently live -> depth-8 pinned structurally), the per-batch NaN row
// range is found by an INDEX scan that overlaps the in-flight loads, and
// every chunk is stored unconditionally with a per-lane cndmask select
// (in_gap ? interpolated : copied). No cross-block sync anywhere.
__global__ __launch_bounds__(256) void interp_v7(const v4* __restrict__ x4,
                                                 v4* __restrict__ out4) {
  const int tid = threadIdx.x;
  const int b = blockIdx.x / BLOCKS_PER_B;
  const int blk_in_b = blockIdx.x - b * BLOCKS_PER_B;
  const int base_in_b = blk_in_b * BLK_F4;          // f4 offset within batch
  const size_t base = (size_t)b * F4_PER_B + base_in_b;

  // ---- phase 1: issue the 8 main loads, depth-8 in flight, untracked ----
  const v4* bp = x4 + base;                         // block-uniform -> SGPR pair
  v4 d[ELEMS];
#pragma unroll
  for (int k = 0; k < ELEMS; ++k) {
    const unsigned off = (unsigned)((k * 256 + tid) * 16);  // byte offset
    asm volatile("global_load_dwordx4 %0, %1, %2 offset:0"
                 : "=v"(d[k])
                 : "v"(off), "s"(bp));
  }

  // ---- phase 2: NaN row-range scan (overlaps the in-flight loads) ----
  // Coarse: probe column (t,0,0) every 8th row; fine: edges within 7 rows.
  // (Proven in round 5: FETCH 77.5 -> 49.5 MB, passed.)
  const float* xf = (const float*)x4;
  const size_t fbase = (size_t)b * (TT * AD);
  __shared__ int smin[4], smax[4];

  int tmin = TT, tmax = -1;
  {
    const int r = tid * 8;
    const float c = xf[fbase + (size_t)r * AD];
    if (c != c) { tmin = r; tmax = r; }
  }
  block_minmax(tid, tmin, tmax, smin, smax);

  if (tmax < 0) {
    // Gap (1..7 rows) fell between samples (P~1.4%): full column scan.
    tmin = TT; tmax = -1;
#pragma unroll
    for (int k = 0; k < 8; ++k) {
      const int r = k * 256 + tid;
      const float c = xf[fbase + (size_t)r * AD];
      if (c != c) { tmin = min(tmin, r); tmax = max(tmax, r); }
    }
    block_minmax(tid, tmin, tmax, smin, smax);
  } else {
    const int cmin = tmin, cmax = tmax;
    tmin = cmin; tmax = cmax;
    if (tid < 7) {
      const int r = cmin - 1 - tid;
      if (r >= 0) { const float c = xf[fbase + (size_t)r * AD]; if (c != c) tmin = r; }
    } else if (tid >= 64 && tid < 71) {
      const int r = cmax + 1 + (tid - 64);
      if (r < TT) { const float c = xf[fbase + (size_t)r * AD]; if (c != c) tmax = r; }
    }
    block_minmax(tid, tmin, tmax, smin, smax);
  }

  int s, e;
  if (tmax < 0) {                // defensive: no NaN -> in_gap never true
    s = 0; e = 1;
  } else {
    s = tmin - 1;                // row before first NaN
    e = min(tmax + 1, TT - 1);   // row after last NaN
  }

  // Boundary rows (NaN-free by construction) -> LDS.
  __shared__ v4 sxs[AD4], sxe[AD4];
  const size_t batch_base = (size_t)b * F4_PER_B;
  if (tid < AD4) sxs[tid] = x4[batch_base + (size_t)s * AD4 + tid];
  if (tid >= 64 && tid < 64 + AD4) sxe[tid - 64] = x4[batch_base + (size_t)e * AD4 + (tid - 64)];
  __syncthreads();

  // ---- phase 3: drain the pinned loads, then select + store ----
  asm volatile("s_waitcnt vmcnt(0)" ::: "memory");
  __builtin_amdgcn_sched_barrier(0);   // rule #18: keep uses below the wait

  const float inv = 1.0f / (float)(e - s);
#pragma unroll
  for (int k = 0; k < ELEMS; ++k) {
    const int idx = base_in_b + k * 256 + tid;      // f4 index within batch
    const int t = idx / AD4;                        // magic-mul const div
    const int c = idx - t * AD4;
    const bool g = (t > s) && (t < e);              // in gap interior
    const float w = (float)(t - s) * inv;
    const float om = 1.0f - w;
    const v4 a = sxs[c];
    const v4 z = sxe[c];
    v4 r;
    r.x = g ? (a.x * om + z.x * w) : d[k].x;        // v_cndmask, no branch
    r.y = g ? (a.y * om + z.y * w) : d[k].y;
    r.z = g ? (a.z * om + z.z * w) : d[k].z;
    r.w = g ? (a.w * om + z.w * w) : d[k].w;
    out4[base + k * 256 + tid] = r;                 // unconditional store
  }
}

extern "C" void kernel_launch(void* const* d_in, const int* in_sizes, int n_in,
                              void* d_out, int out_size, void* d_ws, size_t ws_size,
                              hipStream_t stream) {
  const v4* x4 = (const v4*)d_in[0];
  v4* out4 = (v4*)d_out;
  interp_v7<<<NBLK, 256, 0, stream>>>(x4, out4);
}